// Round 11
// baseline (87.149 us; speedup 1.0000x reference)
//
#include <hip/hip_runtime.h>
#include <hip/hip_bf16.h>

#define N_TOT 4096
#define BATCH 2048
#define DIM   256
#define NCLS  100
#define NSLC  4            // csum slices
#define NTILE 32           // 4096 / 128
#define NPAIR 528          // NTILE*(NTILE+1)/2
#define NWORK (NPAIR + NCLS * NSLC)   // 928 blocks

typedef __attribute__((ext_vector_type(8))) short short8;
typedef __attribute__((ext_vector_type(4))) float floatx4;
typedef __attribute__((ext_vector_type(4))) unsigned short ushortx4;

__device__ __forceinline__ unsigned short f2bf(float x) {
    __hip_bfloat16 h = __float2bfloat16(x);
    return *(unsigned short*)&h;
}

// ---------------------------------------------------------------------------
// K1 (fused work): blocks [0,NPAIR) = den MFMA tiles; [NPAIR,NWORK) = csums.
//   den: 128x128 tile, BK=32 double-buffered LDS. Rows reg-staged from fp32
//   input (no prep kernel): per-row sq-sums accumulated during staging,
//   bf16 cast + swizzled ds_write; epilogue rescales sim = g*rn_r*rn_c.
//   LDS swizzle (64B rows of 4x16B chunks): chunk c of row r at slot
//   c ^ ((r>>1)&3); staged as 8B halves.
//   csum: class membership from dist column (no lab array); matched rows
//   normalized on the fly in exact fp32.
// ---------------------------------------------------------------------------
__global__ __launch_bounds__(256, 4) void work_kernel(const float* __restrict__ z_i,
                                                      const float* __restrict__ z_j,
                                                      const float* __restrict__ dist,
                                                      float* __restrict__ den_part,
                                                      float* __restrict__ csum_part)
{
    __shared__ short tA[2][128 * 32];    // 2 x 8 KB
    __shared__ short tB[2][128 * 32];    // 2 x 8 KB
    __shared__ float rnA[128], rnB[128]; // 1 KB
    __shared__ float red_rs[2][128];
    __shared__ float red_cs[2][128];

    const int t = threadIdx.x;
    const int lane = t & 63, wv = t >> 6;

    if (blockIdx.x >= NPAIR) {
        // ---------------- csum path ----------------
        const int b = blockIdx.x - NPAIR;          // 0..399
        const int c = b % NCLS;
        const int s = b / NCLS;
        const int m0 = s * 1024 + wv * 256;

        float dv[4];
        #pragma unroll
        for (int g = 0; g < 4; ++g) {
            const int m  = m0 + g * 64 + lane;
            const int dm = (m < BATCH) ? m : m - BATCH;
            dv[g] = dist[(size_t)dm * NCLS + c];
        }
        floatx4 acc = {0.f, 0.f, 0.f, 0.f};
        #pragma unroll
        for (int g = 0; g < 4; ++g) {
            unsigned long long mask = __ballot(dv[g] > 0.5f);
            while (mask) {
                const int bit = __builtin_ctzll(mask);
                mask &= mask - 1;
                const int mm = m0 + g * 64 + bit;
                const float* src = (mm < BATCH) ? z_i + (size_t)mm * DIM
                                                : z_j + (size_t)(mm - BATCH) * DIM;
                const floatx4 v = *(const floatx4*)(src + lane * 4);
                float sq = v[0]*v[0] + v[1]*v[1] + v[2]*v[2] + v[3]*v[3];
                #pragma unroll
                for (int sh = 32; sh; sh >>= 1) sq += __shfl_xor(sq, sh);
                const float rn = 1.0f / sqrtf(sq);
                acc[0] += v[0]*rn; acc[1] += v[1]*rn;
                acc[2] += v[2]*rn; acc[3] += v[3]*rn;
            }
        }
        float* cred = (float*)tA;   // reuse LDS: [4][256] floats
        *(floatx4*)&cred[wv * DIM + lane * 4] = acc;
        __syncthreads();
        if (t < DIM)
            csum_part[((size_t)s * NCLS + c) * DIM + t] =
                cred[0*DIM + t] + cred[1*DIM + t] + cred[2*DIM + t] + cred[3*DIM + t];
        return;
    }

    // ---------------- den path ----------------
    int p = blockIdx.x;
    int bi = 0;
    while (p >= NTILE - bi) { p -= NTILE - bi; ++bi; }
    const int bj = bi + p;

    const int row0 = bi * 128, col0 = bj * 128;
    const float* srcA = (row0 < BATCH) ? z_i + (size_t)row0 * DIM
                                       : z_j + (size_t)(row0 - BATCH) * DIM;
    const float* srcB = (col0 < BATCH) ? z_i + (size_t)col0 * DIM
                                       : z_j + (size_t)(col0 - BATCH) * DIM;

    const int wy = wv >> 1, wx = wv & 1;
    const int lr = lane & 15;
    const int lg = lane >> 4;            // 0..3  (16B chunk of the K=32 slab)
    const int sl8 = t & 7;               // 8B slot within 64B LDS row
    const int sr  = t >> 3;              // 0..31 base row for staging

    float sqA[4] = {0.f,0.f,0.f,0.f};
    float sqB[4] = {0.f,0.f,0.f,0.f};
    floatx4 acc[4][4] = {};

    auto STAGE = [&](int kt, int buf) {
        #pragma unroll
        for (int q = 0; q < 4; ++q) {
            const int r = sr + 32 * q;
            const floatx4 va = *(const floatx4*)(srcA + (size_t)r * DIM + kt * 32 + sl8 * 4);
            const floatx4 vb = *(const floatx4*)(srcB + (size_t)r * DIM + kt * 32 + sl8 * 4);
            sqA[q] += va[0]*va[0] + va[1]*va[1] + va[2]*va[2] + va[3]*va[3];
            sqB[q] += vb[0]*vb[0] + vb[1]*vb[1] + vb[2]*vb[2] + vb[3]*vb[3];
            ushortx4 pa, pb;
            pa[0]=f2bf(va[0]); pa[1]=f2bf(va[1]); pa[2]=f2bf(va[2]); pa[3]=f2bf(va[3]);
            pb[0]=f2bf(vb[0]); pb[1]=f2bf(vb[1]); pb[2]=f2bf(vb[2]); pb[3]=f2bf(vb[3]);
            const int byte = r * 64 + (((sl8 >> 1) ^ ((r >> 1) & 3)) << 4) + (sl8 & 1) * 8;
            *(ushortx4*)((char*)tA[buf] + byte) = pa;
            *(ushortx4*)((char*)tB[buf] + byte) = pb;
        }
    };
    auto COMPUTE = [&](int buf) {
        short8 a[4], bb[4];
        #pragma unroll
        for (int i = 0; i < 4; ++i) {
            const int row = wy * 64 + i * 16 + lr;
            const int sl  = lg ^ ((row >> 1) & 3);
            a[i] = *(const short8*)((const char*)tA[buf] + row * 64 + sl * 16);
        }
        #pragma unroll
        for (int j = 0; j < 4; ++j) {
            const int col = wx * 64 + j * 16 + lr;
            const int sl  = lg ^ ((col >> 1) & 3);
            bb[j] = *(const short8*)((const char*)tB[buf] + col * 64 + sl * 16);
        }
        #pragma unroll
        for (int i = 0; i < 4; ++i)
            #pragma unroll
            for (int j = 0; j < 4; ++j)
                acc[i][j] = __builtin_amdgcn_mfma_f32_16x16x32_bf16(a[i], bb[j], acc[i][j], 0, 0, 0);
    };

    STAGE(0, 0);
    __syncthreads();
    int cur = 0;
    #pragma unroll
    for (int kt = 0; kt < 8; ++kt) {
        if (kt < 7) STAGE(kt + 1, cur ^ 1);
        COMPUTE(cur);
        __syncthreads();
        cur ^= 1;
    }

    // per-row inverse norms: reduce sq over the 8 lanes sharing each row
    #pragma unroll
    for (int q = 0; q < 4; ++q) {
        float a = sqA[q], b2 = sqB[q];
        a  += __shfl_xor(a, 1);  a  += __shfl_xor(a, 2);  a  += __shfl_xor(a, 4);
        b2 += __shfl_xor(b2, 1); b2 += __shfl_xor(b2, 2); b2 += __shfl_xor(b2, 4);
        if (sl8 == 0) {
            const int r = sr + 32 * q;
            rnA[r] = 1.0f / sqrtf(a);
            rnB[r] = 1.0f / sqrtf(b2);
        }
    }
    __syncthreads();

    // prefetch the needed inverse norms
    float rnRow[4][4], rnCol[4];
    #pragma unroll
    for (int i = 0; i < 4; ++i)
        #pragma unroll
        for (int r = 0; r < 4; ++r)
            rnRow[i][r] = rnA[wy * 64 + i * 16 + lg * 4 + r];
    #pragma unroll
    for (int j = 0; j < 4; ++j)
        rnCol[j] = rnB[wx * 64 + j * 16 + lr];

    // epilogue: e = off-diag exp(g * rn_r * rn_c); row sums + col sums
    float rs[4][4] = {};
    float cs[4]    = {};
    #pragma unroll
    for (int i = 0; i < 4; ++i) {
        #pragma unroll
        for (int j = 0; j < 4; ++j) {
            const int gcol = col0 + wx * 64 + j * 16 + lr;
            #pragma unroll
            for (int r = 0; r < 4; ++r) {
                const int grow = row0 + wy * 64 + i * 16 + lg * 4 + r;
                const float e = (grow == gcol) ? 0.0f
                              : __expf(acc[i][j][r] * rnRow[i][r] * rnCol[j]);
                rs[i][r] += e;
                cs[j]    += e;
            }
        }
    }
    #pragma unroll
    for (int i = 0; i < 4; ++i)
        #pragma unroll
        for (int r = 0; r < 4; ++r) {
            float v = rs[i][r];
            v += __shfl_xor(v, 1); v += __shfl_xor(v, 2);
            v += __shfl_xor(v, 4); v += __shfl_xor(v, 8);
            rs[i][r] = v;
        }
    if (lr == 0)
        #pragma unroll
        for (int i = 0; i < 4; ++i)
            #pragma unroll
            for (int r = 0; r < 4; ++r)
                red_rs[wx][wy * 64 + i * 16 + lg * 4 + r] = rs[i][r];

    #pragma unroll
    for (int j = 0; j < 4; ++j) {
        float v = cs[j];
        v += __shfl_xor(v, 16); v += __shfl_xor(v, 32);
        cs[j] = v;
    }
    if (lane < 16)
        #pragma unroll
        for (int j = 0; j < 4; ++j)
            red_cs[wy][wx * 64 + j * 16 + lr] = cs[j];

    __syncthreads();
    if (t < 128) {
        den_part[(size_t)bj * N_TOT + row0 + t] = red_rs[0][t] + red_rs[1][t];
        if (bi != bj)
            den_part[(size_t)bi * N_TOT + col0 + t] = red_cs[0][t] + red_cs[1][t];
    }
}

// ---------------------------------------------------------------------------
// K2: per-row finalize (self-normalizing, self-labeling) + last-block reduce.
//     nom = zn.csum[c] - 1; den = sum of 32 panel partials.
// ---------------------------------------------------------------------------
__global__ __launch_bounds__(256) void final_kernel(const float* __restrict__ z_i,
                                                    const float* __restrict__ z_j,
                                                    const float* __restrict__ dist,
                                                    const float* __restrict__ csum_part,
                                                    const float* __restrict__ den_part,
                                                    float* __restrict__ partial,
                                                    int* __restrict__ counter,
                                                    float* __restrict__ out)
{
    const int t = threadIdx.x;
    const int lane = t & 63, wv = t >> 6;

    float bsum = 0.0f;
    #pragma unroll
    for (int it = 0; it < 2; ++it) {
        const int n  = blockIdx.x * 8 + it * 4 + wv;
        const int dm = (n < BATCH) ? n : n - BATCH;

        // label via ballot on the one-hot row
        float d0 = 0.f, d1 = 0.f;
        if (lane < 50) {
            d0 = dist[(size_t)dm * NCLS + 2 * lane];
            d1 = dist[(size_t)dm * NCLS + 2 * lane + 1];
        }
        const unsigned long long m0 = __ballot(d0 > 0.5f);
        const unsigned long long m1 = __ballot(d1 > 0.5f);
        const int c = m0 ? 2 * __builtin_ctzll(m0) : 2 * __builtin_ctzll(m1) + 1;

        // normalized row on the fly
        const float* src = (n < BATCH) ? z_i + (size_t)n * DIM
                                       : z_j + (size_t)(n - BATCH) * DIM;
        floatx4 zv = *(const floatx4*)(src + lane * 4);
        float sq = zv[0]*zv[0] + zv[1]*zv[1] + zv[2]*zv[2] + zv[3]*zv[3];
        #pragma unroll
        for (int sh = 32; sh; sh >>= 1) sq += __shfl_xor(sq, sh);
        const float rn = 1.0f / sqrtf(sq);
        zv[0]*=rn; zv[1]*=rn; zv[2]*=rn; zv[3]*=rn;

        floatx4 sv = {0.f, 0.f, 0.f, 0.f};
        #pragma unroll
        for (int s = 0; s < NSLC; ++s)
            sv += *(const floatx4*)(csum_part + ((size_t)s * NCLS + c) * DIM + lane * 4);

        float pd = zv[0]*sv[0] + zv[1]*sv[1] + zv[2]*sv[2] + zv[3]*sv[3];
        float dd = (lane < NTILE) ? den_part[(size_t)lane * N_TOT + n] : 0.0f;
        #pragma unroll
        for (int sh = 32; sh; sh >>= 1) {
            pd += __shfl_xor(pd, sh);
            dd += __shfl_xor(dd, sh);
        }
        bsum += (pd - 1.0f) / dd;
    }

    __shared__ float w[4];
    __shared__ int amlast;
    if (lane == 0) w[wv] = bsum;
    __syncthreads();
    if (t == 0) {
        partial[blockIdx.x] = w[0] + w[1] + w[2] + w[3];
        __threadfence();
        amlast = (atomicAdd(counter, 1) == (int)gridDim.x - 1);
    }
    __syncthreads();
    if (amlast) {
        __threadfence();
        float s = partial[t] + partial[t + 256];
        #pragma unroll
        for (int sh = 32; sh; sh >>= 1) s += __shfl_xor(s, sh);
        if (lane == 0) w[wv] = s;
        __syncthreads();
        if (t == 0)
            out[0] = (w[0] + w[1] + w[2] + w[3]) / (float)N_TOT;
    }
}

// ---------------------------------------------------------------------------
extern "C" void kernel_launch(void* const* d_in, const int* in_sizes, int n_in,
                              void* d_out, int out_size, void* d_ws, size_t ws_size,
                              hipStream_t stream)
{
    const float* z_i  = (const float*)d_in[0];
    const float* z_j  = (const float*)d_in[1];
    // d_in[2] (z_n) unused by the reference
    const float* dist = (const float*)d_in[3];

    char* ws = (char*)d_ws;
    float* csum_part = (float*)ws;                         // 400 KB
    float* den_part  = (float*)(ws + 512u * 1024);         // 512 KB
    float* partial   = (float*)(ws + 1024u * 1024);        // 2 KB
    int*   counter   = (int*)  (ws + 1026u * 1024);        // 4 B

    float* out = (float*)d_out;

    hipMemsetAsync(counter, 0, 4, stream);
    hipLaunchKernelGGL(work_kernel, dim3(NWORK), dim3(256), 0, stream,
                       z_i, z_j, dist, den_part, csum_part);
    hipLaunchKernelGGL(final_kernel, dim3(N_TOT / 8), dim3(256), 0, stream,
                       z_i, z_j, dist, csum_part, den_part, partial, counter, out);
}

// Round 12
// 46.015 us; speedup vs baseline: 1.8939x; 1.8939x over previous
//
#include <hip/hip_runtime.h>
#include <hip/hip_bf16.h>

#define N_TOT 4096
#define BATCH 2048
#define DIM   256
#define NCLS  100
#define NSLC  4            // csum slices
#define NTILE 32           // 4096 / 128
#define NPAIR 528          // NTILE*(NTILE+1)/2
#define NWORK (NPAIR + NCLS * NSLC)   // 928 blocks

typedef __attribute__((ext_vector_type(8))) short short8;
typedef __attribute__((ext_vector_type(4))) float floatx4;
typedef __attribute__((ext_vector_type(4))) unsigned short ushortx4;

__device__ __forceinline__ unsigned short f2bf(float x) {
    __hip_bfloat16 h = __float2bfloat16(x);
    return *(unsigned short*)&h;
}

// ---------------------------------------------------------------------------
// K1 (fused work): blocks [0,NPAIR) = den MFMA tiles; [NPAIR,NWORK) = csums.
//   den: 128x128 tile, BK=32 double-buffered LDS. Rows reg-staged from fp32
//   input (no prep kernel): per-row sq-sums accumulated during staging,
//   bf16 cast + swizzled ds_write; epilogue rescales sim = g*rn_r*rn_c.
//   Register budget: launch_bounds(256,3) -> ~170 VGPR cap (acc 64 AGPR +
//   frags 32 + staging ~16 fits; (256,4)'s 128 cap caused the R11 spill).
//   LDS swizzle (64B rows of 4x16B chunks): chunk c of row r at slot
//   c ^ ((r>>1)&3); staged as 8B halves.
//   csum: class membership from dist column (no lab array); matched rows
//   normalized on the fly in exact fp32.
// ---------------------------------------------------------------------------
__global__ __launch_bounds__(256, 3) void work_kernel(const float* __restrict__ z_i,
                                                      const float* __restrict__ z_j,
                                                      const float* __restrict__ dist,
                                                      float* __restrict__ den_part,
                                                      float* __restrict__ csum_part)
{
    __shared__ short tA[2][128 * 32];    // 2 x 8 KB
    __shared__ short tB[2][128 * 32];    // 2 x 8 KB
    __shared__ float rnA[128], rnB[128]; // 1 KB
    __shared__ float red_rs[2][128];
    __shared__ float red_cs[2][128];

    const int t = threadIdx.x;
    const int lane = t & 63, wv = t >> 6;

    if (blockIdx.x >= NPAIR) {
        // ---------------- csum path ----------------
        const int b = blockIdx.x - NPAIR;          // 0..399
        const int c = b % NCLS;
        const int s = b / NCLS;
        const int m0 = s * 1024 + wv * 256;

        float dv[4];
        #pragma unroll
        for (int g = 0; g < 4; ++g) {
            const int m  = m0 + g * 64 + lane;
            const int dm = (m < BATCH) ? m : m - BATCH;
            dv[g] = dist[(size_t)dm * NCLS + c];
        }
        floatx4 acc = {0.f, 0.f, 0.f, 0.f};
        #pragma unroll
        for (int g = 0; g < 4; ++g) {
            unsigned long long mask = __ballot(dv[g] > 0.5f);
            while (mask) {
                const int bit = __builtin_ctzll(mask);
                mask &= mask - 1;
                const int mm = m0 + g * 64 + bit;
                const float* src = (mm < BATCH) ? z_i + (size_t)mm * DIM
                                                : z_j + (size_t)(mm - BATCH) * DIM;
                const floatx4 v = *(const floatx4*)(src + lane * 4);
                float sq = v[0]*v[0] + v[1]*v[1] + v[2]*v[2] + v[3]*v[3];
                #pragma unroll
                for (int sh = 32; sh; sh >>= 1) sq += __shfl_xor(sq, sh);
                const float rn = 1.0f / sqrtf(sq);
                acc[0] += v[0]*rn; acc[1] += v[1]*rn;
                acc[2] += v[2]*rn; acc[3] += v[3]*rn;
            }
        }
        float* cred = (float*)tA;   // reuse LDS: [4][256] floats
        *(floatx4*)&cred[wv * DIM + lane * 4] = acc;
        __syncthreads();
        if (t < DIM)
            csum_part[((size_t)s * NCLS + c) * DIM + t] =
                cred[0*DIM + t] + cred[1*DIM + t] + cred[2*DIM + t] + cred[3*DIM + t];
        return;
    }

    // ---------------- den path ----------------
    int p = blockIdx.x;
    int bi = 0;
    while (p >= NTILE - bi) { p -= NTILE - bi; ++bi; }
    const int bj = bi + p;

    const int row0 = bi * 128, col0 = bj * 128;
    const float* srcA = (row0 < BATCH) ? z_i + (size_t)row0 * DIM
                                       : z_j + (size_t)(row0 - BATCH) * DIM;
    const float* srcB = (col0 < BATCH) ? z_i + (size_t)col0 * DIM
                                       : z_j + (size_t)(col0 - BATCH) * DIM;

    const int wy = wv >> 1, wx = wv & 1;
    const int lr = lane & 15;
    const int lg = lane >> 4;            // 0..3  (16B chunk of the K=32 slab)
    const int sl8 = t & 7;               // 8B slot within 64B LDS row
    const int sr  = t >> 3;              // 0..31 base row for staging

    float sqA[4] = {0.f,0.f,0.f,0.f};
    float sqB[4] = {0.f,0.f,0.f,0.f};
    floatx4 acc[4][4] = {};

    // A-pass then B-pass, unroll 2: caps in-flight staging registers.
    auto STAGE = [&](int kt, int buf) {
        #pragma unroll 2
        for (int q = 0; q < 4; ++q) {
            const int r = sr + 32 * q;
            const floatx4 va = *(const floatx4*)(srcA + (size_t)r * DIM + kt * 32 + sl8 * 4);
            sqA[q] += va[0]*va[0] + va[1]*va[1] + va[2]*va[2] + va[3]*va[3];
            ushortx4 pa;
            pa[0]=f2bf(va[0]); pa[1]=f2bf(va[1]); pa[2]=f2bf(va[2]); pa[3]=f2bf(va[3]);
            const int byte = r * 64 + (((sl8 >> 1) ^ ((r >> 1) & 3)) << 4) + (sl8 & 1) * 8;
            *(ushortx4*)((char*)tA[buf] + byte) = pa;
        }
        #pragma unroll 2
        for (int q = 0; q < 4; ++q) {
            const int r = sr + 32 * q;
            const floatx4 vb = *(const floatx4*)(srcB + (size_t)r * DIM + kt * 32 + sl8 * 4);
            sqB[q] += vb[0]*vb[0] + vb[1]*vb[1] + vb[2]*vb[2] + vb[3]*vb[3];
            ushortx4 pb;
            pb[0]=f2bf(vb[0]); pb[1]=f2bf(vb[1]); pb[2]=f2bf(vb[2]); pb[3]=f2bf(vb[3]);
            const int byte = r * 64 + (((sl8 >> 1) ^ ((r >> 1) & 3)) << 4) + (sl8 & 1) * 8;
            *(ushortx4*)((char*)tB[buf] + byte) = pb;
        }
    };
    auto COMPUTE = [&](int buf) {
        short8 a[4], bb[4];
        #pragma unroll
        for (int i = 0; i < 4; ++i) {
            const int row = wy * 64 + i * 16 + lr;
            const int sl  = lg ^ ((row >> 1) & 3);
            a[i] = *(const short8*)((const char*)tA[buf] + row * 64 + sl * 16);
        }
        #pragma unroll
        for (int j = 0; j < 4; ++j) {
            const int col = wx * 64 + j * 16 + lr;
            const int sl  = lg ^ ((col >> 1) & 3);
            bb[j] = *(const short8*)((const char*)tB[buf] + col * 64 + sl * 16);
        }
        #pragma unroll
        for (int i = 0; i < 4; ++i)
            #pragma unroll
            for (int j = 0; j < 4; ++j)
                acc[i][j] = __builtin_amdgcn_mfma_f32_16x16x32_bf16(a[i], bb[j], acc[i][j], 0, 0, 0);
    };

    STAGE(0, 0);
    __syncthreads();
    int cur = 0;
    #pragma unroll
    for (int kt = 0; kt < 8; ++kt) {
        if (kt < 7) STAGE(kt + 1, cur ^ 1);
        COMPUTE(cur);
        __syncthreads();
        cur ^= 1;
    }

    // per-row inverse norms: reduce sq over the 8 lanes sharing each row
    #pragma unroll
    for (int q = 0; q < 4; ++q) {
        float a = sqA[q], b2 = sqB[q];
        a  += __shfl_xor(a, 1);  a  += __shfl_xor(a, 2);  a  += __shfl_xor(a, 4);
        b2 += __shfl_xor(b2, 1); b2 += __shfl_xor(b2, 2); b2 += __shfl_xor(b2, 4);
        if (sl8 == 0) {
            const int r = sr + 32 * q;
            rnA[r] = 1.0f / sqrtf(a);
            rnB[r] = 1.0f / sqrtf(b2);
        }
    }
    __syncthreads();

    // prefetch the needed inverse norms
    float rnRow[4][4], rnCol[4];
    #pragma unroll
    for (int i = 0; i < 4; ++i)
        #pragma unroll
        for (int r = 0; r < 4; ++r)
            rnRow[i][r] = rnA[wy * 64 + i * 16 + lg * 4 + r];
    #pragma unroll
    for (int j = 0; j < 4; ++j)
        rnCol[j] = rnB[wx * 64 + j * 16 + lr];

    // epilogue: e = off-diag exp(g * rn_r * rn_c); row sums + col sums
    float rs[4][4] = {};
    float cs[4]    = {};
    #pragma unroll
    for (int i = 0; i < 4; ++i) {
        #pragma unroll
        for (int j = 0; j < 4; ++j) {
            const int gcol = col0 + wx * 64 + j * 16 + lr;
            #pragma unroll
            for (int r = 0; r < 4; ++r) {
                const int grow = row0 + wy * 64 + i * 16 + lg * 4 + r;
                const float e = (grow == gcol) ? 0.0f
                              : __expf(acc[i][j][r] * rnRow[i][r] * rnCol[j]);
                rs[i][r] += e;
                cs[j]    += e;
            }
        }
    }
    #pragma unroll
    for (int i = 0; i < 4; ++i)
        #pragma unroll
        for (int r = 0; r < 4; ++r) {
            float v = rs[i][r];
            v += __shfl_xor(v, 1); v += __shfl_xor(v, 2);
            v += __shfl_xor(v, 4); v += __shfl_xor(v, 8);
            rs[i][r] = v;
        }
    if (lr == 0)
        #pragma unroll
        for (int i = 0; i < 4; ++i)
            #pragma unroll
            for (int r = 0; r < 4; ++r)
                red_rs[wx][wy * 64 + i * 16 + lg * 4 + r] = rs[i][r];

    #pragma unroll
    for (int j = 0; j < 4; ++j) {
        float v = cs[j];
        v += __shfl_xor(v, 16); v += __shfl_xor(v, 32);
        cs[j] = v;
    }
    if (lane < 16)
        #pragma unroll
        for (int j = 0; j < 4; ++j)
            red_cs[wy][wx * 64 + j * 16 + lr] = cs[j];

    __syncthreads();
    if (t < 128) {
        den_part[(size_t)bj * N_TOT + row0 + t] = red_rs[0][t] + red_rs[1][t];
        if (bi != bj)
            den_part[(size_t)bi * N_TOT + col0 + t] = red_cs[0][t] + red_cs[1][t];
    }
}

// ---------------------------------------------------------------------------
// K2: per-row finalize (self-normalizing, self-labeling) + last-block reduce.
//     nom = zn.csum[c] - 1; den = sum of 32 panel partials.
// ---------------------------------------------------------------------------
__global__ __launch_bounds__(256) void final_kernel(const float* __restrict__ z_i,
                                                    const float* __restrict__ z_j,
                                                    const float* __restrict__ dist,
                                                    const float* __restrict__ csum_part,
                                                    const float* __restrict__ den_part,
                                                    float* __restrict__ partial,
                                                    int* __restrict__ counter,
                                                    float* __restrict__ out)
{
    const int t = threadIdx.x;
    const int lane = t & 63, wv = t >> 6;

    float bsum = 0.0f;
    #pragma unroll
    for (int it = 0; it < 2; ++it) {
        const int n  = blockIdx.x * 8 + it * 4 + wv;
        const int dm = (n < BATCH) ? n : n - BATCH;

        // label via ballot on the one-hot row
        float d0 = 0.f, d1 = 0.f;
        if (lane < 50) {
            d0 = dist[(size_t)dm * NCLS + 2 * lane];
            d1 = dist[(size_t)dm * NCLS + 2 * lane + 1];
        }
        const unsigned long long m0 = __ballot(d0 > 0.5f);
        const unsigned long long m1 = __ballot(d1 > 0.5f);
        const int c = m0 ? 2 * __builtin_ctzll(m0) : 2 * __builtin_ctzll(m1) + 1;

        // normalized row on the fly
        const float* src = (n < BATCH) ? z_i + (size_t)n * DIM
                                       : z_j + (size_t)(n - BATCH) * DIM;
        floatx4 zv = *(const floatx4*)(src + lane * 4);
        float sq = zv[0]*zv[0] + zv[1]*zv[1] + zv[2]*zv[2] + zv[3]*zv[3];
        #pragma unroll
        for (int sh = 32; sh; sh >>= 1) sq += __shfl_xor(sq, sh);
        const float rn = 1.0f / sqrtf(sq);
        zv[0]*=rn; zv[1]*=rn; zv[2]*=rn; zv[3]*=rn;

        floatx4 sv = {0.f, 0.f, 0.f, 0.f};
        #pragma unroll
        for (int s = 0; s < NSLC; ++s)
            sv += *(const floatx4*)(csum_part + ((size_t)s * NCLS + c) * DIM + lane * 4);

        float pd = zv[0]*sv[0] + zv[1]*sv[1] + zv[2]*sv[2] + zv[3]*sv[3];
        float dd = (lane < NTILE) ? den_part[(size_t)lane * N_TOT + n] : 0.0f;
        #pragma unroll
        for (int sh = 32; sh; sh >>= 1) {
            pd += __shfl_xor(pd, sh);
            dd += __shfl_xor(dd, sh);
        }
        bsum += (pd - 1.0f) / dd;
    }

    __shared__ float w[4];
    __shared__ int amlast;
    if (lane == 0) w[wv] = bsum;
    __syncthreads();
    if (t == 0) {
        partial[blockIdx.x] = w[0] + w[1] + w[2] + w[3];
        __threadfence();
        amlast = (atomicAdd(counter, 1) == (int)gridDim.x - 1);
    }
    __syncthreads();
    if (amlast) {
        __threadfence();
        float s = partial[t] + partial[t + 256];
        #pragma unroll
        for (int sh = 32; sh; sh >>= 1) s += __shfl_xor(s, sh);
        if (lane == 0) w[wv] = s;
        __syncthreads();
        if (t == 0)
            out[0] = (w[0] + w[1] + w[2] + w[3]) / (float)N_TOT;
    }
}

// ---------------------------------------------------------------------------
extern "C" void kernel_launch(void* const* d_in, const int* in_sizes, int n_in,
                              void* d_out, int out_size, void* d_ws, size_t ws_size,
                              hipStream_t stream)
{
    const float* z_i  = (const float*)d_in[0];
    const float* z_j  = (const float*)d_in[1];
    // d_in[2] (z_n) unused by the reference
    const float* dist = (const float*)d_in[3];

    char* ws = (char*)d_ws;
    float* csum_part = (float*)ws;                         // 400 KB
    float* den_part  = (float*)(ws + 512u * 1024);         // 512 KB
    float* partial   = (float*)(ws + 1024u * 1024);        // 2 KB
    int*   counter   = (int*)  (ws + 1026u * 1024);        // 4 B

    float* out = (float*)d_out;

    hipMemsetAsync(counter, 0, 4, stream);
    hipLaunchKernelGGL(work_kernel, dim3(NWORK), dim3(256), 0, stream,
                       z_i, z_j, dist, den_part, csum_part);
    hipLaunchKernelGGL(final_kernel, dim3(N_TOT / 8), dim3(256), 0, stream,
                       z_i, z_j, dist, csum_part, den_part, partial, counter, out);
}

// Round 13
// 39.653 us; speedup vs baseline: 2.1978x; 1.1604x over previous
//
#include <hip/hip_runtime.h>
#include <hip/hip_bf16.h>

#define N_TOT 4096
#define BATCH 2048
#define DIM   256
#define NCLS  100
#define NSLC  4            // csum slices
#define NTILE 32           // 4096 / 128
#define NPAIR 528          // NTILE*(NTILE+1)/2
#define NWORK (NPAIR + NCLS * NSLC)   // 928 blocks (= 8 * 116, XCD-swizzlable)

typedef __attribute__((ext_vector_type(8))) short short8;
typedef __attribute__((ext_vector_type(4))) float floatx4;
typedef __attribute__((ext_vector_type(4))) unsigned short ushortx4;

typedef __attribute__((address_space(1))) const unsigned int as1c_uint;
typedef __attribute__((address_space(3))) unsigned int as3_uint;

// async global->LDS, 16B per lane; lds dest is wave-uniform base (+lane*16 by HW)
__device__ __forceinline__ void gload_lds16(const void* g, void* lds_base) {
    __builtin_amdgcn_global_load_lds((as1c_uint*)g, (as3_uint*)lds_base, 16, 0, 0);
}

__device__ __forceinline__ unsigned short f2bf(float x) {
    __hip_bfloat16 h = __float2bfloat16(x);
    return *(unsigned short*)&h;
}

// ---------------------------------------------------------------------------
// K1: normalize rows of concat(z_i, z_j) -> bf16 zb only; labels via ballot;
//     zero final counter. (fp32 normalized copy eliminated: consumers
//     re-normalize from source exactly.)
// ---------------------------------------------------------------------------
__global__ __launch_bounds__(256) void prep_kernel(const float* __restrict__ z_i,
                                                   const float* __restrict__ z_j,
                                                   const float* __restrict__ dist,
                                                   unsigned short* __restrict__ zb,
                                                   int* __restrict__ lab,
                                                   int* __restrict__ counter)
{
    const int t = threadIdx.x;
    const int lane = t & 63, wv = t >> 6;
    if (blockIdx.x == 0 && t == 0) *counter = 0;

    #pragma unroll
    for (int it = 0; it < 2; ++it) {
        const int n = blockIdx.x * 8 + it * 4 + wv;
        const float* src = (n < BATCH) ? (z_i + (size_t)n * DIM)
                                       : (z_j + (size_t)(n - BATCH) * DIM);
        const floatx4 v = *(const floatx4*)(src + lane * 4);
        float ss = v[0]*v[0] + v[1]*v[1] + v[2]*v[2] + v[3]*v[3];
        #pragma unroll
        for (int s = 32; s; s >>= 1) ss += __shfl_xor(ss, s);
        const float rn = 1.0f / sqrtf(ss);

        ushortx4 zp;
        zp[0] = f2bf(v[0]*rn); zp[1] = f2bf(v[1]*rn);
        zp[2] = f2bf(v[2]*rn); zp[3] = f2bf(v[3]*rn);
        *(ushortx4*)(zb + (size_t)n * DIM + lane * 4) = zp;

        if (n < BATCH) {
            float d0 = 0.f, d1 = 0.f;
            if (lane < 50) {
                d0 = dist[(size_t)n * NCLS + 2 * lane];
                d1 = dist[(size_t)n * NCLS + 2 * lane + 1];
            }
            const unsigned long long m0 = __ballot(d0 > 0.5f);
            const unsigned long long m1 = __ballot(d1 > 0.5f);
            if (lane == 0) {
                const int l = m0 ? 2 * __builtin_ctzll(m0)
                                 : 2 * __builtin_ctzll(m1) + 1;
                lab[n] = l;
                lab[n + BATCH] = l;
            }
        }
    }
}

// ---------------------------------------------------------------------------
// K2 (fused): XCD-swizzled grid. sid<NPAIR = den MFMA tiles; else csums.
//     den: 128x128 tile, BK=32 double-buffered LDS via global_load_lds
//     (R6-verified swizzle: slot = chunk ^ ((row>>1)&3), inverse on source).
//     csum: lab-gated rows normalized on the fly in exact fp32.
// ---------------------------------------------------------------------------
__global__ __launch_bounds__(256, 4) void work_kernel(const __hip_bfloat16* __restrict__ zbp,
                                                      const float* __restrict__ z_i,
                                                      const float* __restrict__ z_j,
                                                      const int* __restrict__ lab,
                                                      float* __restrict__ den_part,
                                                      float* __restrict__ csum_part)
{
    __shared__ short tA[2][128 * 32];    // 2 x 8 KB
    __shared__ short tB[2][128 * 32];    // 2 x 8 KB
    __shared__ float red_rs[2][128];
    __shared__ float red_cs[2][128];
    __shared__ float cred[4][DIM];       // csum reduction

    const int t = threadIdx.x;
    const int lane = t & 63, wv = t >> 6;

    // XCD-bijective swizzle: 928 = 8 * 116
    const int sid = (blockIdx.x & 7) * (NWORK / 8) + (blockIdx.x >> 3);

    if (sid >= NPAIR) {
        // ---------------- csum path ----------------
        const int b = sid - NPAIR;                 // 0..399
        const int c = b % NCLS;
        const int s = b / NCLS;
        const int m0 = s * 1024 + wv * 256;

        floatx4 acc = {0.f, 0.f, 0.f, 0.f};
        #pragma unroll
        for (int g = 0; g < 4; ++g) {
            const int m = m0 + g * 64 + lane;
            unsigned long long mask = __ballot(lab[m] == c);
            while (mask) {
                const int bit = __builtin_ctzll(mask);
                mask &= mask - 1;
                const int mm = m0 + g * 64 + bit;
                const float* src = (mm < BATCH) ? z_i + (size_t)mm * DIM
                                                : z_j + (size_t)(mm - BATCH) * DIM;
                const floatx4 v = *(const floatx4*)(src + lane * 4);
                float sq = v[0]*v[0] + v[1]*v[1] + v[2]*v[2] + v[3]*v[3];
                #pragma unroll
                for (int sh = 32; sh; sh >>= 1) sq += __shfl_xor(sq, sh);
                const float rn = 1.0f / sqrtf(sq);
                acc[0] += v[0]*rn; acc[1] += v[1]*rn;
                acc[2] += v[2]*rn; acc[3] += v[3]*rn;
            }
        }
        *(floatx4*)&cred[wv][lane * 4] = acc;
        __syncthreads();
        if (t < DIM)
            csum_part[((size_t)s * NCLS + c) * DIM + t] =
                cred[0][t] + cred[1][t] + cred[2][t] + cred[3][t];
        return;
    }

    // ---------------- den path ----------------
    int p = sid;
    int bi = 0;
    while (p >= NTILE - bi) { p -= NTILE - bi; ++bi; }
    const int bj = bi + p;

    const int wy = wv >> 1, wx = wv & 1;
    const int lr = lane & 15;
    const int lg = lane >> 4;            // 0..3  (16B chunk of the K=32 slab)
    const int sr = lane >> 2;            // 0..15 row-in-q for staging
    const int sslot = lane & 3;          // LDS slot for staging

    const short* z = (const short*)zbp;
    const int row0 = bi * 128;
    const int col0 = bj * 128;

    floatx4 acc[4][4] = {};

    auto STAGE = [&](int kt, int buf) {
        #pragma unroll
        for (int qi = 0; qi < 2; ++qi) {
            const int q = wv * 2 + qi;               // 0..7, 1 KB each (16 rows)
            const int r = q * 16 + sr;
            const int g = sslot ^ ((r >> 1) & 3);    // global chunk for this slot
            gload_lds16(z + (size_t)(row0 + r) * DIM + kt * 32 + g * 8,
                        (char*)tA[buf] + q * 1024);
            gload_lds16(z + (size_t)(col0 + r) * DIM + kt * 32 + g * 8,
                        (char*)tB[buf] + q * 1024);
        }
    };
    auto COMPUTE = [&](int buf) {
        short8 a[4], bb[4];
        #pragma unroll
        for (int i = 0; i < 4; ++i) {
            const int row = wy * 64 + i * 16 + lr;
            const int sl  = lg ^ ((row >> 1) & 3);
            a[i] = *(const short8*)((const char*)tA[buf] + row * 64 + sl * 16);
        }
        #pragma unroll
        for (int j = 0; j < 4; ++j) {
            const int col = wx * 64 + j * 16 + lr;
            const int sl  = lg ^ ((col >> 1) & 3);
            bb[j] = *(const short8*)((const char*)tB[buf] + col * 64 + sl * 16);
        }
        #pragma unroll
        for (int i = 0; i < 4; ++i)
            #pragma unroll
            for (int j = 0; j < 4; ++j)
                acc[i][j] = __builtin_amdgcn_mfma_f32_16x16x32_bf16(a[i], bb[j], acc[i][j], 0, 0, 0);
    };

    STAGE(0, 0);
    __syncthreads();
    int cur = 0;
    #pragma unroll
    for (int kt = 0; kt < 8; ++kt) {
        if (kt < 7) STAGE(kt + 1, cur ^ 1);
        COMPUTE(cur);
        __syncthreads();
        cur ^= 1;
    }

    // ---- epilogue: e = off-diag exp(sim); row sums + col sums
    float rs[4][4] = {};
    float cs[4]    = {};
    #pragma unroll
    for (int i = 0; i < 4; ++i) {
        #pragma unroll
        for (int j = 0; j < 4; ++j) {
            const int gcol = col0 + wx * 64 + j * 16 + lr;
            #pragma unroll
            for (int r = 0; r < 4; ++r) {
                const int grow = row0 + wy * 64 + i * 16 + lg * 4 + r;
                const float e = (grow == gcol) ? 0.0f : __expf(acc[i][j][r]);
                rs[i][r] += e;
                cs[j]    += e;
            }
        }
    }
    #pragma unroll
    for (int i = 0; i < 4; ++i)
        #pragma unroll
        for (int r = 0; r < 4; ++r) {
            float v = rs[i][r];
            v += __shfl_xor(v, 1); v += __shfl_xor(v, 2);
            v += __shfl_xor(v, 4); v += __shfl_xor(v, 8);
            rs[i][r] = v;
        }
    if (lr == 0)
        #pragma unroll
        for (int i = 0; i < 4; ++i)
            #pragma unroll
            for (int r = 0; r < 4; ++r)
                red_rs[wx][wy * 64 + i * 16 + lg * 4 + r] = rs[i][r];

    #pragma unroll
    for (int j = 0; j < 4; ++j) {
        float v = cs[j];
        v += __shfl_xor(v, 16); v += __shfl_xor(v, 32);
        cs[j] = v;
    }
    if (lane < 16)
        #pragma unroll
        for (int j = 0; j < 4; ++j)
            red_cs[wy][wx * 64 + j * 16 + lr] = cs[j];

    __syncthreads();
    if (t < 128) {
        den_part[(size_t)bj * N_TOT + row0 + t] = red_rs[0][t] + red_rs[1][t];
        if (bi != bj)
            den_part[(size_t)bi * N_TOT + col0 + t] = red_cs[0][t] + red_cs[1][t];
    }
}

// ---------------------------------------------------------------------------
// K3: per-row finalize (self-normalizing from source) + last-block reduce.
//     nom = zn.csum[lab[n]] - 1; den = sum of 32 panel partials.
// ---------------------------------------------------------------------------
__global__ __launch_bounds__(256) void final_kernel(const float* __restrict__ z_i,
                                                    const float* __restrict__ z_j,
                                                    const int* __restrict__ lab,
                                                    const float* __restrict__ csum_part,
                                                    const float* __restrict__ den_part,
                                                    float* __restrict__ partial,
                                                    int* __restrict__ counter,
                                                    float* __restrict__ out)
{
    const int t = threadIdx.x;
    const int lane = t & 63, wv = t >> 6;

    float bsum = 0.0f;
    #pragma unroll
    for (int it = 0; it < 2; ++it) {
        const int n = blockIdx.x * 8 + it * 4 + wv;
        const int c = lab[n];

        const float* src = (n < BATCH) ? z_i + (size_t)n * DIM
                                       : z_j + (size_t)(n - BATCH) * DIM;
        floatx4 zv = *(const floatx4*)(src + lane * 4);
        float sq = zv[0]*zv[0] + zv[1]*zv[1] + zv[2]*zv[2] + zv[3]*zv[3];
        #pragma unroll
        for (int sh = 32; sh; sh >>= 1) sq += __shfl_xor(sq, sh);
        const float rn = 1.0f / sqrtf(sq);
        zv[0]*=rn; zv[1]*=rn; zv[2]*=rn; zv[3]*=rn;

        floatx4 sv = {0.f, 0.f, 0.f, 0.f};
        #pragma unroll
        for (int s = 0; s < NSLC; ++s)
            sv += *(const floatx4*)(csum_part + ((size_t)s * NCLS + c) * DIM + lane * 4);

        float pd = zv[0]*sv[0] + zv[1]*sv[1] + zv[2]*sv[2] + zv[3]*sv[3];
        float dd = (lane < NTILE) ? den_part[(size_t)lane * N_TOT + n] : 0.0f;
        #pragma unroll
        for (int sh = 32; sh; sh >>= 1) {
            pd += __shfl_xor(pd, sh);
            dd += __shfl_xor(dd, sh);
        }
        bsum += (pd - 1.0f) / dd;
    }

    __shared__ float w[4];
    __shared__ int amlast;
    if (lane == 0) w[wv] = bsum;
    __syncthreads();
    if (t == 0) {
        partial[blockIdx.x] = w[0] + w[1] + w[2] + w[3];
        __threadfence();
        amlast = (atomicAdd(counter, 1) == (int)gridDim.x - 1);
    }
    __syncthreads();
    if (amlast) {
        __threadfence();
        float s = partial[t] + partial[t + 256];
        #pragma unroll
        for (int sh = 32; sh; sh >>= 1) s += __shfl_xor(s, sh);
        if (lane == 0) w[wv] = s;
        __syncthreads();
        if (t == 0)
            out[0] = (w[0] + w[1] + w[2] + w[3]) / (float)N_TOT;
    }
}

// ---------------------------------------------------------------------------
extern "C" void kernel_launch(void* const* d_in, const int* in_sizes, int n_in,
                              void* d_out, int out_size, void* d_ws, size_t ws_size,
                              hipStream_t stream)
{
    const float* z_i  = (const float*)d_in[0];
    const float* z_j  = (const float*)d_in[1];
    // d_in[2] (z_n) unused by the reference
    const float* dist = (const float*)d_in[3];

    char* ws = (char*)d_ws;
    unsigned short* zb = (unsigned short*)ws;                       // 2 MB
    int*   lab       = (int*)  (ws + 2u * 1024 * 1024);             // 16 KB
    float* csum_part = (float*)(ws + 2u * 1024 * 1024 + 16 * 1024); // 400 KB
    float* den_part  = (float*)(ws + 3u * 1024 * 1024);             // 512 KB
    float* partial   = (float*)(ws + 4u * 1024 * 1024);             // 2 KB
    int*   counter   = (int*)  (ws + 4u * 1024 * 1024 + 2048);      // 4 B

    float* out = (float*)d_out;

    hipLaunchKernelGGL(prep_kernel, dim3(512), dim3(256), 0, stream,
                       z_i, z_j, dist, zb, lab, counter);
    hipLaunchKernelGGL(work_kernel, dim3(NWORK), dim3(256), 0, stream,
                       (const __hip_bfloat16*)zb, z_i, z_j, lab, den_part, csum_part);
    hipLaunchKernelGGL(final_kernel, dim3(N_TOT / 8), dim3(256), 0, stream,
                       z_i, z_j, lab, csum_part, den_part, partial, counter, out);
}